// Round 8
// baseline (497.765 us; speedup 1.0000x reference)
//
#include <hip/hip_runtime.h>

#define NN 100000
#define FIN 128
#define HD 32
#define EE 3200000
#define SLAB 84             // per-node record slab; deg ~ Poisson(32), 84 = +9.2 sigma

typedef unsigned int uint;
typedef unsigned short ushort;
typedef float vfloat4 __attribute__((ext_vector_type(4)));   // clang vector: nontemporal-ok

__device__ __forceinline__ ushort f2bf(float f) {
    uint b = __float_as_uint(f);
    return (ushort)((b + 0x7FFFu + ((b >> 16) & 1u)) >> 16);
}

// values < 2^31 and non-negative: for int64, low dword suffices
__device__ __forceinline__ int load_idx32_nt(const int* __restrict__ ei, long long pos, int is64) {
    return is64 ? __builtin_nontemporal_load(ei + pos * 2)
                : __builtin_nontemporal_load(ei + pos);
}

// ---------------- zero the per-node cursors ----------------
__global__ __launch_bounds__(512) void zero_ncur(int* __restrict__ ncur) {
    int i = blockIdx.x * 512 + threadIdx.x;
    if (i < NN) ncur[i] = 0;
}

// ---------------- scatter: direct per-node slab binning (1 fetch-add/edge) ----
// Replaces the entire two-phase sort (passA/scans/sortC/passB record passes).
// Within-node record order is non-deterministic (atomic race) — same as the
// old passB LDS-atomic race; only fp sum order changes, within tolerance.
// rec = {row17 | bf15(wt)<<17}
__global__ __launch_bounds__(512) void scatter_kernel(const int* __restrict__ ei,
                                                      const float* __restrict__ wt,
                                                      int* __restrict__ ncur,
                                                      uint* __restrict__ erecF) {
    __shared__ int sis64;
    int tid = threadIdx.x;
    if (tid < 64) {   // inline dtype detect: hi dwords of first 256 slots all zero => int64
        uint v = 0;
#pragma unroll
        for (int r = 0; r < 4; r++) v |= ((const uint*)ei)[2 * (tid + 64 * r) + 1];
        unsigned long long nz = __ballot(v != 0u);
        if (tid == 0) sis64 = (nz == 0ULL) ? 1 : 0;
    }
    __syncthreads();
    int is64 = sis64;
    int stride = gridDim.x * 512;
    for (int e = blockIdx.x * 512 + tid; e < EE; e += stride) {
        int row = load_idx32_nt(ei, e, is64);
        int col = load_idx32_nt(ei, (long long)EE + e, is64);
        uint nb = __float_as_uint(__builtin_nontemporal_load(wt + e));
        uint enc = ((nb + 0x8000u) >> 16) & 0x7FFFu;   // bf16 round, drop sign(=0)
        int pos = atomicAdd(&ncur[col], 1);            // global fetch-add (L2-resident ctr)
        erecF[col * SLAB + pos] = (uint)row | (enc << 17);
    }
}

// ---------------- dinv: per-node weighted degree from slab ----------------
__global__ __launch_bounds__(256) void dinv_kernel(const uint* __restrict__ erecF,
                                                   const int* __restrict__ ncur,
                                                   float* __restrict__ dinv) {
    int i = blockIdx.x * 256 + threadIdx.x;
    if (i >= NN) return;
    const uint* p = erecF + i * SLAB;
    int c = ncur[i];
    float s0 = 0.f, s1 = 0.f, s2 = 0.f, s3 = 0.f;
    int k = 0;
    for (; k + 4 <= c; k += 4) {
        s0 += __uint_as_float((p[k + 0] >> 17) << 16);
        s1 += __uint_as_float((p[k + 1] >> 17) << 16);
        s2 += __uint_as_float((p[k + 2] >> 17) << 16);
        s3 += __uint_as_float((p[k + 3] >> 17) << 16);
    }
    for (; k < c; k++) s0 += __uint_as_float((p[k] >> 17) << 16);
    dinv[i] = rsqrtf(1.0f + ((s0 + s1) + (s2 + s3)));   // 1 = self-loop weight
}

// ---------------- xw = x @ [Wc_z | Wc_r | Wc_h]  (f32 VALU, bf16 output) -------
// Output layout per node: 32 features x 8B = 256B row.
// Feature j at byte 8j: { word0 = z_j | r_j<<16, word1 = h_j } (bf16 each).
// One aligned 8B load per lane per edge in agg_gate. dinv[row] folded here.
__global__ __launch_bounds__(256) void gemm_xw_kernel(
        const float* __restrict__ x,
        const float* __restrict__ Wz, const float* __restrict__ Wr, const float* __restrict__ Wh,
        const float* __restrict__ dinv,
        ushort* __restrict__ xw16) {
    __shared__ float Bs[128 * 96];   // Bs[k*96 + c], k GLOBAL (0..127)
    __shared__ float AsT[8 * 128];   // AsT[kk*128 + row], kk local (0..7)
    int tid = threadIdx.x;
    int tx = tid & 31, ty = tid >> 5;
    int rowBase = blockIdx.x * 128;

    for (int e = tid; e < 4096; e += 256) { int k = e >> 5, c = e & 31; Bs[k * 96 + c]      = Wz[e]; }
    for (int e = tid; e < 4096; e += 256) { int k = e >> 5, c = e & 31; Bs[k * 96 + 32 + c] = Wr[e]; }
    for (int e = tid; e < 4096; e += 256) { int k = e >> 5, c = e & 31; Bs[k * 96 + 64 + c] = Wh[e]; }

    float acc0[16], acc1[16], acc2[16];
#pragma unroll
    for (int r = 0; r < 16; r++) { acc0[r] = 0.f; acc1[r] = 0.f; acc2[r] = 0.f; }

    int lr = tid >> 1;
    int lc = (tid & 1) * 4;
    for (int k0 = 0; k0 < 128; k0 += 8) {
        __syncthreads();
        int gr = rowBase + lr;
        vfloat4 a4 = (vfloat4)(0.f);
        if (gr < NN) a4 = __builtin_nontemporal_load((const vfloat4*)(x + (long long)gr * FIN + k0 + lc));
        AsT[(lc + 0) * 128 + lr] = a4.x;
        AsT[(lc + 1) * 128 + lr] = a4.y;
        AsT[(lc + 2) * 128 + lr] = a4.z;
        AsT[(lc + 3) * 128 + lr] = a4.w;
        __syncthreads();
#pragma unroll
        for (int kk = 0; kk < 8; kk++) {
            float b0 = Bs[(k0 + kk) * 96 + tx];
            float b1 = Bs[(k0 + kk) * 96 + 32 + tx];
            float b2 = Bs[(k0 + kk) * 96 + 64 + tx];
            const float4* ap = (const float4*)(AsT + kk * 128 + ty * 16);
            float4 a0 = ap[0], a1 = ap[1], a2 = ap[2], a3 = ap[3];
            float av[16] = {a0.x,a0.y,a0.z,a0.w, a1.x,a1.y,a1.z,a1.w,
                            a2.x,a2.y,a2.z,a2.w, a3.x,a3.y,a3.z,a3.w};
#pragma unroll
            for (int r = 0; r < 16; r++) {
                acc0[r] = fmaf(av[r], b0, acc0[r]);
                acc1[r] = fmaf(av[r], b1, acc1[r]);
                acc2[r] = fmaf(av[r], b2, acc2[r]);
            }
        }
    }
#pragma unroll
    for (int r = 0; r < 16; r++) {
        int gr = rowBase + ty * 16 + r;
        if (gr < NN) {
            float di = dinv[gr];
            ushort* o = xw16 + (long long)gr * 128;   // 256B row
            uint w0 = (uint)f2bf(acc0[r] * di) | ((uint)f2bf(acc1[r] * di) << 16);
            uint w1 = (uint)f2bf(acc2[r] * di);
            uint2 pk; pk.x = w0; pk.y = w1;
            *(uint2*)(o + 4 * tx) = pk;               // 8B aligned, coalesced
        }
    }
}

// ---------------- fused gather-aggregate + GRU gates + head ----------------
// 32-lane group per node; 16 nodes / 512-thread block; NN = 6250*16 exactly.
// xw16 rows pre-scaled by dinv[row]:  agg = dinv[col]*(sum w_e*xw'[row_e] + xw'[col])
// One 8B load per lane per edge (interleaved layout). Records in per-node
// slabs: beg = i*SLAB, cnt = ncur[i].
// BARRIERS KEPT (register-pressure fences): removing them -> VGPR 80,
// occupancy 22% (rounds 3/4). With barriers, VGPR stays at 32 and occupancy
// is LDS-limited at 4 blocks/CU. Unroll-8 first tier (round 6: +3%).
__global__ __launch_bounds__(512) void agg_gate_kernel(
        const uint* __restrict__ erecF, const int* __restrict__ cnt,
        const ushort* __restrict__ xw16, const float* __restrict__ dinv,
        const float* __restrict__ hprev,
        const float* __restrict__ bcz, const float* __restrict__ bcr, const float* __restrict__ bch,
        const float* __restrict__ Wlz, const float* __restrict__ blz,
        const float* __restrict__ Wlr, const float* __restrict__ blr,
        const float* __restrict__ Wlh, const float* __restrict__ blh,
        const float* __restrict__ Whead, const float* __restrict__ bhead,
        float* __restrict__ y, float* __restrict__ hnew) {
    __shared__ float WzT[64 * 32], WrT[64 * 32], WhT[64 * 32];  // WT[k*32+j] = Wl[j*64+k]
    __shared__ float czs[16][32], crs[16][32], chs[16][32], hps[16][32], rhs[16][32];
    __shared__ uint rwsh[16][32];   // staged records per group
    int tid = threadIdx.x;
    for (int e2 = tid; e2 < 2048; e2 += 512) {
        int jj = e2 >> 6, k = e2 & 63;
        WzT[k * 32 + jj] = Wlz[e2];
        WrT[k * 32 + jj] = Wlr[e2];
        WhT[k * 32 + jj] = Wlh[e2];
    }
    int s = tid >> 5, j = tid & 31;
    int i = blockIdx.x * 16 + s;
    int beg = i * SLAB, c = cnt[i], end = beg + c;

    const char* xwb = (const char*)xw16;
    uint jo8 = 8u * (uint)j;            // byte offset of feature j's 8B cell

    float cz = 0.f, cr = 0.f, ch = 0.f;
    int e = beg + j;
    uint vcur = (e < end) ? __builtin_nontemporal_load(erecF + e) : 0u;   // batch 0
    __syncthreads();   // WT staging complete

#define REC(vv, dd)                                                        \
    {                                                                      \
        float w_ = __uint_as_float(((vv) >> 17) << 16);                    \
        cz = fmaf(w_, __uint_as_float((dd).x << 16), cz);                  \
        cr = fmaf(w_, __uint_as_float((dd).x & 0xFFFF0000u), cr);          \
        ch = fmaf(w_, __uint_as_float((dd).y << 16), ch);                  \
    }

    for (int base = beg; base < end; base += 32) {
        rwsh[s][j] = vcur;                      // in-order DS within wave: safe
        int en = base + 32 + j;
        uint vnext = (en < end) ? __builtin_nontemporal_load(erecF + en) : 0u;  // prefetch next batch
        int mm = end - base; if (mm > 32) mm = 32;
        int t = 0;
        for (; t + 8 <= mm; t += 8) {           // 8 x 8B gathers in flight per group
            uint v0 = rwsh[s][t + 0], v1 = rwsh[s][t + 1], v2 = rwsh[s][t + 2], v3 = rwsh[s][t + 3];
            uint v4 = rwsh[s][t + 4], v5 = rwsh[s][t + 5], v6 = rwsh[s][t + 6], v7 = rwsh[s][t + 7];
            uint b0 = (v0 & 0x1FFFFu) * 256u, b1 = (v1 & 0x1FFFFu) * 256u;
            uint b2 = (v2 & 0x1FFFFu) * 256u, b3 = (v3 & 0x1FFFFu) * 256u;
            uint b4 = (v4 & 0x1FFFFu) * 256u, b5 = (v5 & 0x1FFFFu) * 256u;
            uint b6 = (v6 & 0x1FFFFu) * 256u, b7 = (v7 & 0x1FFFFu) * 256u;
            uint2 d0 = *(const uint2*)(xwb + b0 + jo8);
            uint2 d1 = *(const uint2*)(xwb + b1 + jo8);
            uint2 d2 = *(const uint2*)(xwb + b2 + jo8);
            uint2 d3 = *(const uint2*)(xwb + b3 + jo8);
            uint2 d4 = *(const uint2*)(xwb + b4 + jo8);
            uint2 d5 = *(const uint2*)(xwb + b5 + jo8);
            uint2 d6 = *(const uint2*)(xwb + b6 + jo8);
            uint2 d7 = *(const uint2*)(xwb + b7 + jo8);
            REC(v0, d0) REC(v1, d1) REC(v2, d2) REC(v3, d3)
            REC(v4, d4) REC(v5, d5) REC(v6, d6) REC(v7, d7)
        }
        for (; t + 4 <= mm; t += 4) {
            uint v0 = rwsh[s][t + 0], v1 = rwsh[s][t + 1], v2 = rwsh[s][t + 2], v3 = rwsh[s][t + 3];
            uint b0 = (v0 & 0x1FFFFu) * 256u, b1 = (v1 & 0x1FFFFu) * 256u;
            uint b2 = (v2 & 0x1FFFFu) * 256u, b3 = (v3 & 0x1FFFFu) * 256u;
            uint2 d0 = *(const uint2*)(xwb + b0 + jo8);
            uint2 d1 = *(const uint2*)(xwb + b1 + jo8);
            uint2 d2 = *(const uint2*)(xwb + b2 + jo8);
            uint2 d3 = *(const uint2*)(xwb + b3 + jo8);
            REC(v0, d0) REC(v1, d1) REC(v2, d2) REC(v3, d3)
        }
        for (; t < mm; t++) {
            uint v0 = rwsh[s][t];
            uint b0 = (v0 & 0x1FFFFu) * 256u;
            uint2 d0 = *(const uint2*)(xwb + b0 + jo8);
            REC(v0, d0)
        }
        vcur = vnext;
    }
#undef REC

    // self-loop + dinv[col] + bias:  c* = di*(sum + xw'[i]) + bc
    float di = dinv[i];
    uint2 dself = *(const uint2*)(xwb + (uint)i * 256u + jo8);
    czs[s][j] = fmaf(di, cz + __uint_as_float(dself.x << 16), bcz[j]);
    crs[s][j] = fmaf(di, cr + __uint_as_float(dself.x & 0xFFFF0000u), bcr[j]);
    chs[s][j] = fmaf(di, ch + __uint_as_float(dself.y << 16), bch[j]);
    float hp = hprev[(long long)i * HD + j];
    hps[s][j] = hp;
    __syncthreads();   // register-pressure fence + cross-group visibility

    float az = blz[j], arv = blr[j];
#pragma unroll
    for (int k = 0; k < 32; k++) {
        az  = fmaf(WzT[k * 32 + j], czs[s][k], az);
        arv = fmaf(WrT[k * 32 + j], crs[s][k], arv);
    }
#pragma unroll
    for (int k = 0; k < 32; k++) {
        float v = hps[s][k];
        az  = fmaf(WzT[(k + 32) * 32 + j], v, az);
        arv = fmaf(WrT[(k + 32) * 32 + j], v, arv);
    }
    float Z = 1.f / (1.f + __expf(-az));
    float R = 1.f / (1.f + __expf(-arv));
    rhs[s][j] = hp * R;
    __syncthreads();   // register-pressure fence

    float ah = blh[j];
#pragma unroll
    for (int k = 0; k < 32; k++) ah = fmaf(WhT[k * 32 + j], chs[s][k], ah);
#pragma unroll
    for (int k = 0; k < 32; k++) ah = fmaf(WhT[(k + 32) * 32 + j], rhs[s][k], ah);
    float Ht = tanhf(ah);
    float hn = Z * hp + (1.f - Z) * Ht;
    float yv = fmaxf(hn, 0.f) * Whead[j];
#pragma unroll
    for (int m = 16; m; m >>= 1) yv += __shfl_xor(yv, m, 32);
    hnew[(long long)i * HD + j] = hn;
    if (j == 0) y[i] = yv + bhead[0];
}

extern "C" void kernel_launch(void* const* d_in, const int* in_sizes, int n_in,
                              void* d_out, int out_size, void* d_ws, size_t ws_size,
                              hipStream_t stream) {
    const float* x     = (const float*)d_in[0];
    const int*   ei    = (const int*)d_in[1];
    const float* wt    = (const float*)d_in[2];
    const float* hprev = (const float*)d_in[3];
    const float* Wcz = (const float*)d_in[4],  *bcz = (const float*)d_in[5];
    const float* Wlz = (const float*)d_in[6],  *blz = (const float*)d_in[7];
    const float* Wcr = (const float*)d_in[8],  *bcr = (const float*)d_in[9];
    const float* Wlr = (const float*)d_in[10], *blr = (const float*)d_in[11];
    const float* Wch = (const float*)d_in[12], *bch = (const float*)d_in[13];
    const float* Wlh = (const float*)d_in[14], *blh = (const float*)d_in[15];
    const float* Whead = (const float*)d_in[16], *bhead = (const float*)d_in[17];

    float* out_y = (float*)d_out;            // [N]
    float* out_h = (float*)d_out + NN;       // [N,32]

    float* ws = (float*)d_ws;
    int*   ncur  = (int*)ws;                                  // NN (doubles as cnt)
    float* dinv  = ws + NN;                                   // NN
    uint*  erecF = (uint*)(ws + 2LL * NN);                    // NN*SLAB uints (33.6 MB)
    ushort* xw16 = (ushort*)(ws + 2LL * NN + (long long)NN * SLAB);  // NN*128 ushorts (25.6 MB)

    zero_ncur<<<(NN + 511) / 512, 512, 0, stream>>>(ncur);
    scatter_kernel<<<1024, 512, 0, stream>>>(ei, wt, ncur, erecF);
    dinv_kernel<<<(NN + 255) / 256, 256, 0, stream>>>(erecF, ncur, dinv);
    gemm_xw_kernel<<<(NN + 127) / 128, 256, 0, stream>>>(x, Wcz, Wcr, Wch, dinv, xw16);
    agg_gate_kernel<<<NN / 16, 512, 0, stream>>>(
        erecF, ncur, xw16, dinv, hprev, bcz, bcr, bch,
        Wlz, blz, Wlr, blr, Wlh, blh, Whead, bhead, out_y, out_h);
}

// Round 9
// 415.601 us; speedup vs baseline: 1.1977x; 1.1977x over previous
//
#include <hip/hip_runtime.h>

#define NN 100000
#define FIN 128
#define HD 32
#define EE 3200000
#define NBUK 391            // coarse buckets of 256 nodes
#define EPB 6144            // edges per binning chunk (LDS-sort fits in 64KB)
#define NBLK ((EE + EPB - 1) / EPB)   // 521

typedef unsigned int uint;
typedef unsigned short ushort;
typedef float vfloat4 __attribute__((ext_vector_type(4)));   // clang vector: nontemporal-ok

__device__ __forceinline__ ushort f2bf(float f) {
    uint b = __float_as_uint(f);
    return (ushort)((b + 0x7FFFu + ((b >> 16) & 1u)) >> 16);
}
__device__ __forceinline__ float bf2f(ushort u) {
    return __uint_as_float(((uint)u) << 16);
}

// values < 2^31 and non-negative: for int64, low dword suffices
__device__ __forceinline__ int load_idx32(const int* __restrict__ ei, long long pos, int is64) {
    return is64 ? __builtin_nontemporal_load(ei + pos * 2)
                : __builtin_nontemporal_load(ei + pos);
}

// ---------------- passA: coarse histogram (LDS atomics only) + inline dtype detect ----------------
__global__ __launch_bounds__(256) void passA_hist(const int* __restrict__ ei,
                                                  int* __restrict__ blockhist,
                                                  int* __restrict__ flag) {
    __shared__ int hist[NBUK];
    __shared__ int sis64;
    int tid = threadIdx.x, blk = blockIdx.x;
    for (int b = tid; b < NBUK; b += 256) hist[b] = 0;
    if (tid < 64) {   // wave 0: detect int64 vs int32 (hi dwords of first 256 slots all zero => int64)
        uint v = 0;
#pragma unroll
        for (int r = 0; r < 4; r++) v |= ((const uint*)ei)[2 * (tid + 64 * r) + 1];
        unsigned long long nz = __ballot(v != 0u);
        if (tid == 0) sis64 = (nz == 0ULL) ? 1 : 0;
    }
    __syncthreads();
    int is64 = sis64;
    if (blk == 0 && tid == 0) *flag = is64;   // for sortC (runs after scan kernels)
    int e0 = blk * EPB, e1 = e0 + EPB; if (e1 > EE) e1 = EE;
    for (int e = e0 + tid; e < e1; e += 256) {
        int col = load_idx32(ei, (long long)EE + e, is64);
        atomicAdd(&hist[col >> 8], 1);
    }
    __syncthreads();
    for (int b = tid; b < NBUK; b += 256) blockhist[blk * NBUK + b] = hist[b];
}

// ---------------- per-bucket exclusive scan over chunks ----------------
__global__ void scan_bucket(const int* __restrict__ blockhist, int* __restrict__ off_local,
                            int* __restrict__ total) {
    int b = blockIdx.x;          // bucket
    int l = threadIdx.x;         // 0..63 (one wave)
    int run = 0;
    for (int c = 0; c < NBLK; c += 64) {
        int blk = c + l;
        int v = (blk < NBLK) ? blockhist[blk * NBUK + b] : 0;
        int incl = v;
#pragma unroll
        for (int d = 1; d < 64; d <<= 1) {
            int t = __shfl_up(incl, d, 64);
            if (l >= d) incl += t;
        }
        if (blk < NBLK) off_local[blk * NBUK + b] = run + (incl - v);
        run += __shfl(incl, 63, 64);
    }
    if (l == 0) total[b] = run;
}

__global__ void scan_total(const int* __restrict__ total, int* __restrict__ bstart) {
    __shared__ int sd[512];
    int t = threadIdx.x;
    int v = (t < NBUK) ? total[t] : 0;
    sd[t] = v;
    __syncthreads();
    for (int off = 1; off < 512; off <<= 1) {
        int x = (t >= off) ? sd[t - off] : 0;
        __syncthreads();
        sd[t] += x;
        __syncthreads();
    }
    if (t < NBUK) bstart[t] = sd[t] - v;
    if (t == NBUK - 1) bstart[NBUK] = sd[t];
}

// ---------------- sortC: LDS-sorted chunk scatter (coalesced writes) --------
// Records placed bucket-sorted in LDS, then streamed out contiguously.
// rec = {row17 | bf15(wt)<<17, col32}
__global__ __launch_bounds__(512) void sortC_kernel(const int* __restrict__ ei,
                                                    const float* __restrict__ wt,
                                                    const int* __restrict__ bstart,
                                                    const int* __restrict__ off_local,
                                                    const int* __restrict__ blockhist,
                                                    uint2* __restrict__ erec2,
                                                    const int* __restrict__ flag) {
    __shared__ uint2 lrec[EPB];      // 49152 B
    __shared__ int lcombo[NBUK];     // bstart[b] + off_local[blk][b] - lstart[b]
    __shared__ int lcur[NBUK];
    int tid = threadIdx.x, blk = blockIdx.x;
    if (tid < 64) {                  // wave 0: exclusive scan of this chunk's hist
        int run = 0;
        for (int c = 0; c < NBUK; c += 64) {
            int b = c + tid;
            int v = (b < NBUK) ? blockhist[blk * NBUK + b] : 0;
            int incl = v;
#pragma unroll
            for (int d = 1; d < 64; d <<= 1) {
                int t2 = __shfl_up(incl, d, 64);
                if (tid >= d) incl += t2;
            }
            if (b < NBUK) {
                int ls = run + incl - v;
                lcur[b] = ls;
                lcombo[b] = bstart[b] + off_local[blk * NBUK + b] - ls;
            }
            run += __shfl(incl, 63, 64);
        }
    }
    __syncthreads();
    int is64 = *flag;
    int e0 = blk * EPB, e1 = e0 + EPB; if (e1 > EE) e1 = EE;
    for (int e = e0 + tid; e < e1; e += 512) {
        int row = load_idx32(ei, e, is64);
        int col = load_idx32(ei, (long long)EE + e, is64);
        uint nb = __float_as_uint(__builtin_nontemporal_load(wt + e));
        uint enc = ((nb + 0x8000u) >> 16) & 0x7FFFu;   // bf16 round, drop sign(=0)
        int pos = atomicAdd(&lcur[col >> 8], 1);       // LDS atomic
        uint2 r; r.x = (uint)row | (enc << 17); r.y = (uint)col;
        lrec[pos] = r;
    }
    __syncthreads();
    int m = e1 - e0;
    for (int slot = tid; slot < m; slot += 512) {
        uint2 r = lrec[slot];
        int gpos = lcombo[r.y >> 8] + slot;
        erec2[gpos] = r;             // contiguous within each bucket segment
    }
}

// ---------------- passB: per-bucket fine sort + degree/dinv (fused) ----------
__global__ __launch_bounds__(512) void passB_fine(const uint2* __restrict__ erec2,
                                                  const int* __restrict__ bstart,
                                                  uint* __restrict__ erecF,
                                                  int* __restrict__ estart, int* __restrict__ cnt,
                                                  float* __restrict__ dinv) {
    __shared__ int hist[256];
    __shared__ float wsum[256];
    __shared__ int off[256];
    __shared__ int cur[256];
    __shared__ int sd[256];
    int t = threadIdx.x, b = blockIdx.x;
    if (t < 256) { hist[t] = 0; wsum[t] = 0.f; }
    __syncthreads();
    int e0 = bstart[b], e1 = bstart[b + 1];
    for (int e = e0 + t; e < e1; e += 512) {
        uint2 r = erec2[e];
        int cl = (int)(r.y & 255u);
        atomicAdd(&hist[cl], 1);
        atomicAdd(&wsum[cl], __uint_as_float((r.x >> 17) << 16));
    }
    __syncthreads();
    int v = 0;
    if (t < 256) { v = hist[t]; sd[t] = v; }
    __syncthreads();
    for (int o = 1; o < 256; o <<= 1) {
        int x = (t >= o && t < 256) ? sd[t - o] : 0;
        __syncthreads();
        if (t < 256) sd[t] += x;
        __syncthreads();
    }
    if (t < 256) {
        off[t] = sd[t] - v;
        cur[t] = 0;
        int node = b * 256 + t;
        if (node < NN) {
            estart[node] = e0 + off[t];
            cnt[node] = v;
            dinv[node] = rsqrtf(1.0f + wsum[t]);   // 1 = self-loop weight
        }
    }
    __syncthreads();
    for (int e = e0 + t; e < e1; e += 512) {
        uint2 r = erec2[e];
        int cl = (int)(r.y & 255u);
        int p = atomicAdd(&cur[cl], 1);        // LDS atomic
        erecF[e0 + off[cl] + p] = r.x;         // dense per-node-sorted (hot 32KB window)
    }
}

// ---------------- xw = x @ [Wc_z | Wc_r | Wc_h]  (f32 VALU, bf16 output) -------
// Output layout per node: 192B row (96 ushort), NO padding:
//   zr-pair (z_j | r_j<<16) at byte 4j;  h_j at byte 128 + 2j.
// Round 8 showed agg is L2-fill-BW bound at ~2.5 TB/s on DEMAND bytes; the
// 256B row wasted 64B/row (25% of demand). Two loads/edge instead of one.
// dinv[row] folded here. xw16 ALIASES erec2 (dead after passB; same stream).
__global__ __launch_bounds__(256) void gemm_xw_kernel(
        const float* __restrict__ x,
        const float* __restrict__ Wz, const float* __restrict__ Wr, const float* __restrict__ Wh,
        const float* __restrict__ dinv,
        ushort* __restrict__ xw16) {
    __shared__ float Bs[128 * 96];   // Bs[k*96 + c], k GLOBAL (0..127)
    __shared__ float AsT[8 * 128];   // AsT[kk*128 + row], kk local (0..7)
    int tid = threadIdx.x;
    int tx = tid & 31, ty = tid >> 5;
    int rowBase = blockIdx.x * 128;

    for (int e = tid; e < 4096; e += 256) { int k = e >> 5, c = e & 31; Bs[k * 96 + c]      = Wz[e]; }
    for (int e = tid; e < 4096; e += 256) { int k = e >> 5, c = e & 31; Bs[k * 96 + 32 + c] = Wr[e]; }
    for (int e = tid; e < 4096; e += 256) { int k = e >> 5, c = e & 31; Bs[k * 96 + 64 + c] = Wh[e]; }

    float acc0[16], acc1[16], acc2[16];
#pragma unroll
    for (int r = 0; r < 16; r++) { acc0[r] = 0.f; acc1[r] = 0.f; acc2[r] = 0.f; }

    int lr = tid >> 1;
    int lc = (tid & 1) * 4;
    for (int k0 = 0; k0 < 128; k0 += 8) {
        __syncthreads();
        int gr = rowBase + lr;
        vfloat4 a4 = (vfloat4)(0.f);
        if (gr < NN) a4 = __builtin_nontemporal_load((const vfloat4*)(x + (long long)gr * FIN + k0 + lc));
        AsT[(lc + 0) * 128 + lr] = a4.x;
        AsT[(lc + 1) * 128 + lr] = a4.y;
        AsT[(lc + 2) * 128 + lr] = a4.z;
        AsT[(lc + 3) * 128 + lr] = a4.w;
        __syncthreads();
#pragma unroll
        for (int kk = 0; kk < 8; kk++) {
            float b0 = Bs[(k0 + kk) * 96 + tx];
            float b1 = Bs[(k0 + kk) * 96 + 32 + tx];
            float b2 = Bs[(k0 + kk) * 96 + 64 + tx];
            const float4* ap = (const float4*)(AsT + kk * 128 + ty * 16);
            float4 a0 = ap[0], a1 = ap[1], a2 = ap[2], a3 = ap[3];
            float av[16] = {a0.x,a0.y,a0.z,a0.w, a1.x,a1.y,a1.z,a1.w,
                            a2.x,a2.y,a2.z,a2.w, a3.x,a3.y,a3.z,a3.w};
#pragma unroll
            for (int r = 0; r < 16; r++) {
                acc0[r] = fmaf(av[r], b0, acc0[r]);
                acc1[r] = fmaf(av[r], b1, acc1[r]);
                acc2[r] = fmaf(av[r], b2, acc2[r]);
            }
        }
    }
#pragma unroll
    for (int r = 0; r < 16; r++) {
        int gr = rowBase + ty * 16 + r;
        if (gr < NN) {
            float di = dinv[gr];
            ushort* o = xw16 + (long long)gr * 96;    // 192B row
            uint zr = (uint)f2bf(acc0[r] * di) | ((uint)f2bf(acc1[r] * di) << 16);
            *(uint*)(o + 2 * tx) = zr;                // 4B coalesced
            o[64 + tx] = f2bf(acc2[r] * di);          // 2B
        }
    }
}

// ---------------- fused gather-aggregate + GRU gates + head ----------------
// 32-lane group per node; 16 nodes / 512-thread block; NN = 6250*16 exactly.
// xw16 rows pre-scaled by dinv[row]:  agg = dinv[col]*(sum w_e*xw'[row_e] + xw'[col])
// 192B rows, two loads/edge (4B zr + 2B h) — group reads the full 192B row,
// zero padding waste (round 8 post-mortem: agg is demand-BW bound).
// BARRIERS KEPT (register-pressure fences): removing them -> VGPR 80,
// occupancy 22% (rounds 3/4). Unroll-8 first tier (round 6: +3%).
// ABORT SIGNAL: if VGPR > 64 here, this layout change caused it — revert.
__global__ __launch_bounds__(512) void agg_gate_kernel(
        const uint* __restrict__ erecF, const int* __restrict__ estart, const int* __restrict__ cnt,
        const ushort* __restrict__ xw16, const float* __restrict__ dinv,
        const float* __restrict__ hprev,
        const float* __restrict__ bcz, const float* __restrict__ bcr, const float* __restrict__ bch,
        const float* __restrict__ Wlz, const float* __restrict__ blz,
        const float* __restrict__ Wlr, const float* __restrict__ blr,
        const float* __restrict__ Wlh, const float* __restrict__ blh,
        const float* __restrict__ Whead, const float* __restrict__ bhead,
        float* __restrict__ y, float* __restrict__ hnew) {
    __shared__ float WzT[64 * 32], WrT[64 * 32], WhT[64 * 32];  // WT[k*32+j] = Wl[j*64+k]
    __shared__ float czs[16][32], crs[16][32], chs[16][32], hps[16][32], rhs[16][32];
    __shared__ uint rwsh[16][32];   // staged records per group
    int tid = threadIdx.x;
    for (int e2 = tid; e2 < 2048; e2 += 512) {
        int jj = e2 >> 6, k = e2 & 63;
        WzT[k * 32 + jj] = Wlz[e2];
        WrT[k * 32 + jj] = Wlr[e2];
        WhT[k * 32 + jj] = Wlh[e2];
    }
    int s = tid >> 5, j = tid & 31;
    int i = blockIdx.x * 16 + s;
    int beg = estart[i], c = cnt[i], end = beg + c;

    const char* xwb = (const char*)xw16;
    uint jo4 = 4u * (uint)j;            // byte offset of feature j's zr pair
    uint jo2 = 128u + 2u * (uint)j;     // byte offset of feature j's h

    float cz = 0.f, cr = 0.f, ch = 0.f;
    int e = beg + j;
    uint vcur = (e < end) ? __builtin_nontemporal_load(erecF + e) : 0u;   // batch 0
    __syncthreads();   // WT staging complete

#define REC(vv, aa, hh)                                                    \
    {                                                                      \
        float w_ = __uint_as_float(((vv) >> 17) << 16);                    \
        cz = fmaf(w_, __uint_as_float((aa) << 16), cz);                    \
        cr = fmaf(w_, __uint_as_float((aa) & 0xFFFF0000u), cr);            \
        ch = fmaf(w_, bf2f(hh), ch);                                       \
    }

    for (int base = beg; base < end; base += 32) {
        rwsh[s][j] = vcur;                      // in-order DS within wave: safe
        int en = base + 32 + j;
        uint vnext = (en < end) ? __builtin_nontemporal_load(erecF + en) : 0u;  // prefetch next batch
        int mm = end - base; if (mm > 32) mm = 32;
        int t = 0;
        for (; t + 8 <= mm; t += 8) {           // 16 loads in flight per group
            uint v0 = rwsh[s][t + 0], v1 = rwsh[s][t + 1], v2 = rwsh[s][t + 2], v3 = rwsh[s][t + 3];
            uint v4 = rwsh[s][t + 4], v5 = rwsh[s][t + 5], v6 = rwsh[s][t + 6], v7 = rwsh[s][t + 7];
            uint b0 = (v0 & 0x1FFFFu) * 192u, b1 = (v1 & 0x1FFFFu) * 192u;
            uint b2 = (v2 & 0x1FFFFu) * 192u, b3 = (v3 & 0x1FFFFu) * 192u;
            uint b4 = (v4 & 0x1FFFFu) * 192u, b5 = (v5 & 0x1FFFFu) * 192u;
            uint b6 = (v6 & 0x1FFFFu) * 192u, b7 = (v7 & 0x1FFFFu) * 192u;
            uint a0 = *(const uint*)(xwb + b0 + jo4);
            uint a1 = *(const uint*)(xwb + b1 + jo4);
            uint a2 = *(const uint*)(xwb + b2 + jo4);
            uint a3 = *(const uint*)(xwb + b3 + jo4);
            uint a4 = *(const uint*)(xwb + b4 + jo4);
            uint a5 = *(const uint*)(xwb + b5 + jo4);
            uint a6 = *(const uint*)(xwb + b6 + jo4);
            uint a7 = *(const uint*)(xwb + b7 + jo4);
            ushort h0 = *(const ushort*)(xwb + b0 + jo2);
            ushort h1 = *(const ushort*)(xwb + b1 + jo2);
            ushort h2 = *(const ushort*)(xwb + b2 + jo2);
            ushort h3 = *(const ushort*)(xwb + b3 + jo2);
            ushort h4 = *(const ushort*)(xwb + b4 + jo2);
            ushort h5 = *(const ushort*)(xwb + b5 + jo2);
            ushort h6 = *(const ushort*)(xwb + b6 + jo2);
            ushort h7 = *(const ushort*)(xwb + b7 + jo2);
            REC(v0, a0, h0) REC(v1, a1, h1) REC(v2, a2, h2) REC(v3, a3, h3)
            REC(v4, a4, h4) REC(v5, a5, h5) REC(v6, a6, h6) REC(v7, a7, h7)
        }
        for (; t + 4 <= mm; t += 4) {
            uint v0 = rwsh[s][t + 0], v1 = rwsh[s][t + 1], v2 = rwsh[s][t + 2], v3 = rwsh[s][t + 3];
            uint b0 = (v0 & 0x1FFFFu) * 192u, b1 = (v1 & 0x1FFFFu) * 192u;
            uint b2 = (v2 & 0x1FFFFu) * 192u, b3 = (v3 & 0x1FFFFu) * 192u;
            uint a0 = *(const uint*)(xwb + b0 + jo4);
            uint a1 = *(const uint*)(xwb + b1 + jo4);
            uint a2 = *(const uint*)(xwb + b2 + jo4);
            uint a3 = *(const uint*)(xwb + b3 + jo4);
            ushort h0 = *(const ushort*)(xwb + b0 + jo2);
            ushort h1 = *(const ushort*)(xwb + b1 + jo2);
            ushort h2 = *(const ushort*)(xwb + b2 + jo2);
            ushort h3 = *(const ushort*)(xwb + b3 + jo2);
            REC(v0, a0, h0) REC(v1, a1, h1) REC(v2, a2, h2) REC(v3, a3, h3)
        }
        for (; t < mm; t++) {
            uint v0 = rwsh[s][t];
            uint b0 = (v0 & 0x1FFFFu) * 192u;
            uint a0 = *(const uint*)(xwb + b0 + jo4);
            ushort h0 = *(const ushort*)(xwb + b0 + jo2);
            REC(v0, a0, h0)
        }
        vcur = vnext;
    }
#undef REC

    // self-loop + dinv[col] + bias:  c* = di*(sum + xw'[i]) + bc
    float di = dinv[i];
    uint bi = (uint)i * 192u;
    uint zri = *(const uint*)(xwb + bi + jo4);
    float hself = bf2f(*(const ushort*)(xwb + bi + jo2));
    czs[s][j] = fmaf(di, cz + __uint_as_float(zri << 16), bcz[j]);
    crs[s][j] = fmaf(di, cr + __uint_as_float(zri & 0xFFFF0000u), bcr[j]);
    chs[s][j] = fmaf(di, ch + hself, bch[j]);
    float hp = hprev[(long long)i * HD + j];
    hps[s][j] = hp;
    __syncthreads();   // register-pressure fence + cross-group visibility

    float az = blz[j], arv = blr[j];
#pragma unroll
    for (int k = 0; k < 32; k++) {
        az  = fmaf(WzT[k * 32 + j], czs[s][k], az);
        arv = fmaf(WrT[k * 32 + j], crs[s][k], arv);
    }
#pragma unroll
    for (int k = 0; k < 32; k++) {
        float v = hps[s][k];
        az  = fmaf(WzT[(k + 32) * 32 + j], v, az);
        arv = fmaf(WrT[(k + 32) * 32 + j], v, arv);
    }
    float Z = 1.f / (1.f + __expf(-az));
    float R = 1.f / (1.f + __expf(-arv));
    rhs[s][j] = hp * R;
    __syncthreads();   // register-pressure fence

    float ah = blh[j];
#pragma unroll
    for (int k = 0; k < 32; k++) ah = fmaf(WhT[k * 32 + j], chs[s][k], ah);
#pragma unroll
    for (int k = 0; k < 32; k++) ah = fmaf(WhT[(k + 32) * 32 + j], rhs[s][k], ah);
    float Ht = tanhf(ah);
    float hn = Z * hp + (1.f - Z) * Ht;
    float yv = fmaxf(hn, 0.f) * Whead[j];
#pragma unroll
    for (int m = 16; m; m >>= 1) yv += __shfl_xor(yv, m, 32);
    hnew[(long long)i * HD + j] = hn;
    if (j == 0) y[i] = yv + bhead[0];
}

extern "C" void kernel_launch(void* const* d_in, const int* in_sizes, int n_in,
                              void* d_out, int out_size, void* d_ws, size_t ws_size,
                              hipStream_t stream) {
    const float* x     = (const float*)d_in[0];
    const int*   ei    = (const int*)d_in[1];
    const float* wt    = (const float*)d_in[2];
    const float* hprev = (const float*)d_in[3];
    const float* Wcz = (const float*)d_in[4],  *bcz = (const float*)d_in[5];
    const float* Wlz = (const float*)d_in[6],  *blz = (const float*)d_in[7];
    const float* Wcr = (const float*)d_in[8],  *bcr = (const float*)d_in[9];
    const float* Wlr = (const float*)d_in[10], *blr = (const float*)d_in[11];
    const float* Wch = (const float*)d_in[12], *bch = (const float*)d_in[13];
    const float* Wlh = (const float*)d_in[14], *blh = (const float*)d_in[15];
    const float* Whead = (const float*)d_in[16], *bhead = (const float*)d_in[17];

    float* out_y = (float*)d_out;            // [N]
    float* out_h = (float*)d_out + NN;       // [N,32]

    float* ws = (float*)d_ws;
    float* dinv      = ws;                                   // NN f32
    int*   estart    = (int*)(ws + NN);                      // NN
    int*   cnt       = (int*)(ws + 2LL * NN);                // NN
    int*   bstart    = (int*)(ws + 3LL * NN);                // NBUK+1 (pad 512)
    int*   total     = (int*)(ws + 3LL * NN + 512);          // NBUK (pad 512)
    int*   blockhist = (int*)(ws + 3LL * NN + 1024);         // NBLK*NBUK=203711 (pad 204000)
    int*   off_local = (int*)(ws + 3LL * NN + 205024);       // 203711 (pad 204000)
    int*   flag      = (int*)(ws + 3LL * NN + 409024);       // 1 (pad 32)
    uint2*  erec2    = (uint2*)(ws + 3LL * NN + 409056);     // EE uint2 (8B-aligned)
    ushort* xw16     = (ushort*)erec2;                       // ALIAS: NN*192B (19.2MB) <= EE*8B (25.6MB)
    uint*   erecF    = (uint*)(ws + 3LL * NN + 409056 + 2LL * EE);  // EE uint

    passA_hist<<<NBLK, 256, 0, stream>>>(ei, blockhist, flag);
    scan_bucket<<<NBUK, 64, 0, stream>>>(blockhist, off_local, total);
    scan_total<<<1, 512, 0, stream>>>(total, bstart);
    sortC_kernel<<<NBLK, 512, 0, stream>>>(ei, wt, bstart, off_local, blockhist, erec2, flag);
    passB_fine<<<NBUK, 512, 0, stream>>>(erec2, bstart, erecF, estart, cnt, dinv);
    gemm_xw_kernel<<<(NN + 127) / 128, 256, 0, stream>>>(x, Wcz, Wcr, Wch, dinv, xw16);
    agg_gate_kernel<<<NN / 16, 512, 0, stream>>>(
        erecF, estart, cnt, xw16, dinv, hprev, bcz, bcr, bch,
        Wlz, blz, Wlr, blr, Wlh, blh, Whead, bhead, out_y, out_h);
}